// Round 9
// baseline (229.907 us; speedup 1.0000x reference)
//
#include <hip/hip_runtime.h>
#include <math.h>

#define SIGMA_F 32.0f
#define BB 8
#define CC 31
#define HH 512
#define WW 512
#define PLANE (HH * WW)
#define WINR 102                  // max staged rows: 102*128*4B = 52.2KB -> 3 blocks/CU

// ---- compile-time Gaussian weights: W[i] = exp(-i^2 / 2048) ----
constexpr double cexp_neg(double t) {
    double u = -t / 16.0;
    double s = 1.0, term = 1.0;
    for (int k = 1; k < 14; ++k) { term *= u / (double)k; s += term; }
    s = s * s; s = s * s; s = s * s; s = s * s;
    return s;
}
constexpr float gwf(int i) { return (float)cexp_neg((double)(i * i) / 2048.0); }

__device__ constexpr float W[64] = {
    gwf(0),  gwf(1),  gwf(2),  gwf(3),  gwf(4),  gwf(5),  gwf(6),  gwf(7),
    gwf(8),  gwf(9),  gwf(10), gwf(11), gwf(12), gwf(13), gwf(14), gwf(15),
    gwf(16), gwf(17), gwf(18), gwf(19), gwf(20), gwf(21), gwf(22), gwf(23),
    gwf(24), gwf(25), gwf(26), gwf(27), gwf(28), gwf(29), gwf(30), gwf(31),
    gwf(32), gwf(33), gwf(34), gwf(35), gwf(36), gwf(37), gwf(38), gwf(39),
    gwf(40), gwf(41), gwf(42), gwf(43), gwf(44), gwf(45), gwf(46), gwf(47),
    gwf(48), gwf(49), gwf(50), gwf(51), gwf(52), gwf(53), gwf(54), gwf(55),
    gwf(56), gwf(57), gwf(58), gwf(59), gwf(60), gwf(61), gwf(62), 0.0f
};

__global__ __launch_bounds__(256, 2) void blur_fused_kernel(const float* __restrict__ dxn,
                                                            const float* __restrict__ dyn,
                                                            float* __restrict__ blur,
                                                            float* __restrict__ partials) {
    __shared__ __align__(16) float vt[16 * 580];
    __shared__ float smax[4];
    int t = threadIdx.x;
    int blk = blockIdx.x;
    int plane = blk >> 5;
    int band = blk & 31;
    int y0 = band << 4;
    const float* src = (plane < BB) ? dxn + (size_t)plane * PLANE
                                    : dyn + (size_t)(plane - BB) * PLANE;

    for (int c = t; c < 574; c += 256) {
        int L = c - 31;
        int scol = (L < 0) ? -L : ((L > HH - 1) ? 2 * HH - 2 - L : L);
        float acc[16];
        #pragma unroll
        for (int j = 0; j < 16; ++j) acc[j] = 0.0f;
        #pragma unroll
        for (int ro = 0; ro < 78; ++ro) {
            int rr = y0 - 31 + ro;
            int r = (rr < 0) ? -rr : ((rr > HH - 1) ? 2 * HH - 2 - rr : rr);
            float v = src[r * WW + scol];
            #pragma unroll
            for (int j = 0; j < 16; ++j) {
                int wi = ro - j;
                if (wi >= 0 && wi < 63) acc[j] += W[wi] * v;
            }
        }
        #pragma unroll
        for (int j = 0; j < 16; ++j) vt[j * 580 + c] = acc[j];
    }
    __syncthreads();

    float m = -INFINITY;
    int row = t & 15;
    int chunk0 = t >> 4;
    float* dstrow = blur + (size_t)plane * PLANE + (size_t)(y0 + row) * WW;
    const float* vrow = vt + row * 580;
    #pragma unroll
    for (int pass = 0; pass < 2; ++pass) {
        int x0 = (chunk0 + (pass << 4)) << 4;
        float acc[16];
        #pragma unroll
        for (int j = 0; j < 16; ++j) acc[j] = 0.0f;
        const float4* v4 = (const float4*)(vrow + x0);
        #pragma unroll
        for (int mi = 0; mi < 20; ++mi) {
            float4 vv = v4[mi];
            #pragma unroll
            for (int e = 0; e < 4; ++e) {
                float xv = (e == 0) ? vv.x : (e == 1) ? vv.y : (e == 2) ? vv.z : vv.w;
                int k = (mi << 2) + e;
                #pragma unroll
                for (int j = 0; j < 16; ++j) {
                    int wi = k - j;
                    if (wi >= 0 && wi < 63) acc[j] += W[wi] * xv;
                }
            }
        }
        #pragma unroll
        for (int j = 0; j < 16; ++j) m = fmaxf(m, acc[j]);
        float4* dst4 = (float4*)(dstrow + x0);
        #pragma unroll
        for (int q = 0; q < 4; ++q)
            dst4[q] = make_float4(acc[4 * q], acc[4 * q + 1], acc[4 * q + 2], acc[4 * q + 3]);
    }

    for (int off = 32; off; off >>= 1) m = fmaxf(m, __shfl_down(m, off, 64));
    if ((t & 63) == 0) smax[t >> 6] = m;
    __syncthreads();
    if (t == 0)
        partials[blk] = fmaxf(fmaxf(smax[0], smax[1]), fmaxf(smax[2], smax[3]));
}

__global__ __launch_bounds__(256) void reduce_max_kernel(const float* __restrict__ partials,
                                                         float* __restrict__ maxv) {
    int f = blockIdx.x;
    int t = threadIdx.x;
    float m = partials[f * 256 + t];
    __shared__ float smax[4];
    for (int off = 32; off; off >>= 1) m = fmaxf(m, __shfl_down(m, off, 64));
    if ((t & 63) == 0) smax[t >> 6] = m;
    __syncthreads();
    if (t == 0)
        maxv[f] = fmaxf(fmaxf(smax[0], smax[1]), fmaxf(smax[2], smax[3]));
}

// async global->LDS, 16B per lane; LDS dest = wave-uniform base + lane*16
__device__ __forceinline__ void gload_lds16(const float* g, float* l) {
    __builtin_amdgcn_global_load_lds(
        (const __attribute__((address_space(1))) void*)g,
        (__attribute__((address_space(3))) void*)l,
        16, 0, 0);
}

// 64x64 tile per block, 256 threads, 3 blocks/CU (52.2KB LDS cap).
// DYNAMIC row window: per-tile reduce gives Y0 (even) and Ht <= WINR; only
// those rows are staged (row-pairs per gload_lds16, wave-uniform predicate).
// X window fixed 128 cols, aligned. Fallback to direct gather if the x-span
// escapes the 128-col window or Ht > WINR (rare).
__global__ __launch_bounds__(256, 3) void warp_tiled_kernel(const float* __restrict__ xin,
                                                            const float* __restrict__ blur,
                                                            const float* __restrict__ maxv,
                                                            float* __restrict__ warped,
                                                            float2* __restrict__ gridout) {
    __shared__ __align__(16) float stage[WINR * 128];
    __shared__ int rx0[4], rx1[4], ry0[4], ry1[4];
    __shared__ int sbox[3];       // ok, Y0, Ht

    int t = threadIdx.x;
    int bid = blockIdx.x;
    int b = bid & 7;               // XCD j owns batch j
    int tile = bid >> 3;           // row-major tiles within the batch
    int ty0 = (tile >> 3) << 6;
    int tx0 = (tile & 7) << 6;
    int wxs = min(max(tx0 - 32, 0), WW - 128);   // 16B-aligned window start

    float sx = SIGMA_F / maxv[0];
    float sy = SIGMA_F / maxv[1];
    int col = t & 63, row0 = t >> 6;

    float wxa[16], wya[16];
    int pre[16];
    int x0mn = 1 << 30, x0mx = -1, y0mn = 1 << 30, y0mx = -1;

    const float* bdx = blur + (size_t)b * PLANE;
    const float* bdy = blur + (size_t)(BB + b) * PLANE;

    #pragma unroll
    for (int k = 0; k < 16; ++k) {
        int gy = ty0 + row0 + 4 * k;
        int gx = tx0 + col;
        float dxv = bdx[gy * WW + gx] * sx;
        float dyv = bdy[gy * WW + gx] * sy;
        float gnx = 2.0f * ((float)gx + dxv) / 511.0f - 1.0f;
        float gny = 2.0f * ((float)gy + dyv) / 511.0f - 1.0f;
        gridout[((size_t)b * HH + gy) * WW + gx] = make_float2(gnx, gny);
        float ix = (gnx + 1.0f) * 0.5f * 511.0f;
        float iy = (gny + 1.0f) * 0.5f * 511.0f;
        ix = fminf(fmaxf(ix, 0.0f), 511.0f);
        iy = fminf(fmaxf(iy, 0.0f), 511.0f);
        float fx = floorf(ix), fy = floorf(iy);
        float wx = ix - fx, wy = iy - fy;
        int x0 = (int)fx, y0 = (int)fy;
        if (x0 > WW - 2) { x0 = WW - 2; wx = 1.0f; }   // border clamp trick
        if (y0 > HH - 2) { y0 = HH - 2; wy = 1.0f; }
        wxa[k] = wx; wya[k] = wy;
        pre[k] = y0 * 128 + (x0 - wxs);
        x0mn = min(x0mn, x0); x0mx = max(x0mx, x0);
        y0mn = min(y0mn, y0); y0mx = max(y0mx, y0);
    }

    for (int off = 32; off; off >>= 1) {
        x0mn = min(x0mn, __shfl_xor(x0mn, off, 64));
        x0mx = max(x0mx, __shfl_xor(x0mx, off, 64));
        y0mn = min(y0mn, __shfl_xor(y0mn, off, 64));
        y0mx = max(y0mx, __shfl_xor(y0mx, off, 64));
    }
    if ((t & 63) == 0) {
        int wv = t >> 6;
        rx0[wv] = x0mn; rx1[wv] = x0mx; ry0[wv] = y0mn; ry1[wv] = y0mx;
    }
    __syncthreads();
    if (t == 0) {
        int a = rx0[0], bx = rx1[0], c = ry0[0], d = ry1[0];
        #pragma unroll
        for (int i = 1; i < 4; ++i) {
            a = min(a, rx0[i]); bx = max(bx, rx1[i]);
            c = min(c, ry0[i]); d = max(d, ry1[i]);
        }
        int Y0 = c & ~1;                       // even start row
        int Y1r = d + 1;                       // last row needed (<= 511)
        int Ht = Y1r - Y0 + 1;
        int ok = (a >= wxs) && (bx + 1 <= wxs + 127) && (Ht <= WINR);
        sbox[0] = ok; sbox[1] = Y0; sbox[2] = Ht;
    }
    __syncthreads();
    int ok = sbox[0], Y0 = sbox[1], Ht = sbox[2];

    const float* xb = xin + (size_t)b * CC * PLANE;
    float* wb = warped + (size_t)b * CC * PLANE;
    int obase = (ty0 + row0) * WW + tx0 + col;

    if (ok) {
        int wave = t >> 6, lane = t & 63;
        int lrow = lane >> 5, lcol4 = (lane & 31) * 4;
        // lane's address within a 2-row pair: row lrow, 16B chunk lcol4
        const float* gb = xb + (size_t)Y0 * WW + wxs + lrow * WW + lcol4;
        int yoff = Y0 * 128;
        int oa[16];
        #pragma unroll
        for (int k = 0; k < 16; ++k) oa[k] = pre[k] - yoff;

        for (int c = 0; c < CC; ++c) {
            const float* g = gb + (size_t)c * PLANE;
            #pragma unroll
            for (int i = 0; i < 13; ++i) {                 // pairs: (wave+4i)*2 < WINR
                int r0 = (wave + 4 * i) * 2;               // wave-uniform pair row
                if (r0 < Ht)
                    gload_lds16(g + r0 * WW, stage + r0 * 128);
            }
            __syncthreads();                               // window c staged
            float* dstc = wb + (size_t)c * PLANE;
            #pragma unroll
            for (int k = 0; k < 16; ++k) {
                float v00 = stage[oa[k]],       v01 = stage[oa[k] + 1];
                float v10 = stage[oa[k] + 128], v11 = stage[oa[k] + 129];
                float tp = v00 + wxa[k] * (v01 - v00);
                float bt = v10 + wxa[k] * (v11 - v10);
                dstc[obase + k * 4 * WW] = tp + wya[k] * (bt - tp);
            }
            __syncthreads();                               // reads done before overwrite
        }
    } else {
        // rare fallback: direct global gather (identical arithmetic)
        #pragma unroll
        for (int k = 0; k < 16; ++k) {
            int gy = ty0 + row0 + 4 * k;
            int gx = tx0 + col;
            float dxv = bdx[gy * WW + gx] * sx;
            float dyv = bdy[gy * WW + gx] * sy;
            float gnx = 2.0f * ((float)gx + dxv) / 511.0f - 1.0f;
            float gny = 2.0f * ((float)gy + dyv) / 511.0f - 1.0f;
            float ix = (gnx + 1.0f) * 0.5f * 511.0f;
            float iy = (gny + 1.0f) * 0.5f * 511.0f;
            ix = fminf(fmaxf(ix, 0.0f), 511.0f);
            iy = fminf(fmaxf(iy, 0.0f), 511.0f);
            float fx = floorf(ix), fy = floorf(iy);
            float wx = ix - fx, wy = iy - fy;
            int x0 = (int)fx, y0 = (int)fy;
            if (x0 > WW - 2) { x0 = WW - 2; wx = 1.0f; }
            if (y0 > HH - 2) { y0 = HH - 2; wy = 1.0f; }
            int o00 = y0 * WW + x0;
            for (int c = 0; c < CC; ++c) {
                const float* src = xb + (size_t)c * PLANE;
                float v00 = src[o00], v01 = src[o00 + 1];
                float v10 = src[o00 + WW], v11 = src[o00 + WW + 1];
                float tp = v00 + wx * (v01 - v00);
                float bt = v10 + wx * (v11 - v10);
                wb[(size_t)c * PLANE + obase + k * 4 * WW] = tp + wy * (bt - tp);
            }
        }
    }
}

extern "C" void kernel_launch(void* const* d_in, const int* in_sizes, int n_in,
                              void* d_out, int out_size, void* d_ws, size_t ws_size,
                              hipStream_t stream) {
    const float* x   = (const float*)d_in[0];
    const float* dxn = (const float*)d_in[1];
    const float* dyn = (const float*)d_in[2];

    float* ws = (float*)d_ws;
    float* blur     = ws;                       // 16*512*512 floats
    float* partials = ws + 4194304;             // 512 floats
    float* maxv     = ws + 4194304 + 512;       // 2 floats

    float* warped   = (float*)d_out;
    float2* gridout = (float2*)((float*)d_out + (size_t)BB * CC * PLANE);

    blur_fused_kernel<<<16 * 32, 256, 0, stream>>>(dxn, dyn, blur, partials);
    reduce_max_kernel<<<2, 256, 0, stream>>>(partials, maxv);
    warp_tiled_kernel<<<BB * 64, 256, 0, stream>>>(x, blur, maxv, warped, gridout);
}

// Round 10
// 192.298 us; speedup vs baseline: 1.1956x; 1.1956x over previous
//
#include <hip/hip_runtime.h>
#include <math.h>

#define SIGMA_F 32.0f
#define BB 8
#define CC 31
#define HH 512
#define WW 512
#define PLANE (HH * WW)

// ---- compile-time Gaussian weights: W[i] = exp(-i^2 / 2048) ----
constexpr double cexp_neg(double t) {
    double u = -t / 16.0;
    double s = 1.0, term = 1.0;
    for (int k = 1; k < 14; ++k) { term *= u / (double)k; s += term; }
    s = s * s; s = s * s; s = s * s; s = s * s;
    return s;
}
constexpr float gwf(int i) { return (float)cexp_neg((double)(i * i) / 2048.0); }

__device__ constexpr float W[64] = {
    gwf(0),  gwf(1),  gwf(2),  gwf(3),  gwf(4),  gwf(5),  gwf(6),  gwf(7),
    gwf(8),  gwf(9),  gwf(10), gwf(11), gwf(12), gwf(13), gwf(14), gwf(15),
    gwf(16), gwf(17), gwf(18), gwf(19), gwf(20), gwf(21), gwf(22), gwf(23),
    gwf(24), gwf(25), gwf(26), gwf(27), gwf(28), gwf(29), gwf(30), gwf(31),
    gwf(32), gwf(33), gwf(34), gwf(35), gwf(36), gwf(37), gwf(38), gwf(39),
    gwf(40), gwf(41), gwf(42), gwf(43), gwf(44), gwf(45), gwf(46), gwf(47),
    gwf(48), gwf(49), gwf(50), gwf(51), gwf(52), gwf(53), gwf(54), gwf(55),
    gwf(56), gwf(57), gwf(58), gwf(59), gwf(60), gwf(61), gwf(62), 0.0f
};

__global__ __launch_bounds__(256, 2) void blur_fused_kernel(const float* __restrict__ dxn,
                                                            const float* __restrict__ dyn,
                                                            float* __restrict__ blur,
                                                            float* __restrict__ partials) {
    __shared__ __align__(16) float vt[16 * 580];
    __shared__ float smax[4];
    int t = threadIdx.x;
    int blk = blockIdx.x;
    int plane = blk >> 5;
    int band = blk & 31;
    int y0 = band << 4;
    const float* src = (plane < BB) ? dxn + (size_t)plane * PLANE
                                    : dyn + (size_t)(plane - BB) * PLANE;

    for (int c = t; c < 574; c += 256) {
        int L = c - 31;
        int scol = (L < 0) ? -L : ((L > HH - 1) ? 2 * HH - 2 - L : L);
        float acc[16];
        #pragma unroll
        for (int j = 0; j < 16; ++j) acc[j] = 0.0f;
        #pragma unroll
        for (int ro = 0; ro < 78; ++ro) {
            int rr = y0 - 31 + ro;
            int r = (rr < 0) ? -rr : ((rr > HH - 1) ? 2 * HH - 2 - rr : rr);
            float v = src[r * WW + scol];
            #pragma unroll
            for (int j = 0; j < 16; ++j) {
                int wi = ro - j;
                if (wi >= 0 && wi < 63) acc[j] += W[wi] * v;
            }
        }
        #pragma unroll
        for (int j = 0; j < 16; ++j) vt[j * 580 + c] = acc[j];
    }
    __syncthreads();

    float m = -INFINITY;
    int row = t & 15;
    int chunk0 = t >> 4;
    float* dstrow = blur + (size_t)plane * PLANE + (size_t)(y0 + row) * WW;
    const float* vrow = vt + row * 580;
    #pragma unroll
    for (int pass = 0; pass < 2; ++pass) {
        int x0 = (chunk0 + (pass << 4)) << 4;
        float acc[16];
        #pragma unroll
        for (int j = 0; j < 16; ++j) acc[j] = 0.0f;
        const float4* v4 = (const float4*)(vrow + x0);
        #pragma unroll
        for (int mi = 0; mi < 20; ++mi) {
            float4 vv = v4[mi];
            #pragma unroll
            for (int e = 0; e < 4; ++e) {
                float xv = (e == 0) ? vv.x : (e == 1) ? vv.y : (e == 2) ? vv.z : vv.w;
                int k = (mi << 2) + e;
                #pragma unroll
                for (int j = 0; j < 16; ++j) {
                    int wi = k - j;
                    if (wi >= 0 && wi < 63) acc[j] += W[wi] * xv;
                }
            }
        }
        #pragma unroll
        for (int j = 0; j < 16; ++j) m = fmaxf(m, acc[j]);
        float4* dst4 = (float4*)(dstrow + x0);
        #pragma unroll
        for (int q = 0; q < 4; ++q)
            dst4[q] = make_float4(acc[4 * q], acc[4 * q + 1], acc[4 * q + 2], acc[4 * q + 3]);
    }

    for (int off = 32; off; off >>= 1) m = fmaxf(m, __shfl_down(m, off, 64));
    if ((t & 63) == 0) smax[t >> 6] = m;
    __syncthreads();
    if (t == 0)
        partials[blk] = fmaxf(fmaxf(smax[0], smax[1]), fmaxf(smax[2], smax[3]));
}

__global__ __launch_bounds__(256) void reduce_max_kernel(const float* __restrict__ partials,
                                                         float* __restrict__ maxv) {
    int f = blockIdx.x;
    int t = threadIdx.x;
    float m = partials[f * 256 + t];
    __shared__ float smax[4];
    for (int off = 32; off; off >>= 1) m = fmaxf(m, __shfl_down(m, off, 64));
    if ((t & 63) == 0) smax[t >> 6] = m;
    __syncthreads();
    if (t == 0)
        maxv[f] = fmaxf(fmaxf(smax[0], smax[1]), fmaxf(smax[2], smax[3]));
}

// async global->LDS, 16B per lane; LDS dest = wave-uniform base + lane*16
__device__ __forceinline__ void gload_lds16(const float* g, float* l) {
    __builtin_amdgcn_global_load_lds(
        (const __attribute__((address_space(1))) void*)g,
        (__attribute__((address_space(3))) void*)l,
        16, 0, 0);
}

// Round-8 structure (64x64 tile, 256 thr, 128-row dynamic window, 2 blocks/CU)
// + bank-conflict XOR swizzle. LDS slot (rw, chunk16B) holds global chunk
// (chunk ^ ((rw&7)<<2)): staged by pre-swizzling the per-lane GLOBAL source
// (LDS dest stays linear, as gload_lds requires); read addresses apply the
// same involution. Staged row parity makes (rw&7) lane-constant -> swizzle
// costs nothing in the staging loop.
__global__ __launch_bounds__(256) void warp_tiled_kernel(const float* __restrict__ xin,
                                                         const float* __restrict__ blur,
                                                         const float* __restrict__ maxv,
                                                         float* __restrict__ warped,
                                                         float2* __restrict__ gridout) {
    __shared__ __align__(16) float stage[128 * 128];
    __shared__ int rx0[4], rx1[4], ry0[4], ry1[4];
    __shared__ int sbox[3];       // ok, Y0, Ht

    int t = threadIdx.x;
    int bid = blockIdx.x;
    int b = bid & 7;               // XCD j owns batch j
    int tile = bid >> 3;           // row-major tiles within the batch
    int ty0 = (tile >> 3) << 6;
    int tx0 = (tile & 7) << 6;
    int wxs = min(max(tx0 - 32, 0), WW - 128);   // 16B-aligned window start

    float sx = SIGMA_F / maxv[0];
    float sy = SIGMA_F / maxv[1];
    int col = t & 63, row0 = t >> 6;

    float wxa[16], wya[16];
    int pre[16];
    int x0mn = 1 << 30, x0mx = -1, y0mn = 1 << 30, y0mx = -1;

    const float* bdx = blur + (size_t)b * PLANE;
    const float* bdy = blur + (size_t)(BB + b) * PLANE;

    #pragma unroll
    for (int k = 0; k < 16; ++k) {
        int gy = ty0 + row0 + 4 * k;
        int gx = tx0 + col;
        float dxv = bdx[gy * WW + gx] * sx;
        float dyv = bdy[gy * WW + gx] * sy;
        float gnx = 2.0f * ((float)gx + dxv) / 511.0f - 1.0f;
        float gny = 2.0f * ((float)gy + dyv) / 511.0f - 1.0f;
        gridout[((size_t)b * HH + gy) * WW + gx] = make_float2(gnx, gny);
        float ix = (gnx + 1.0f) * 0.5f * 511.0f;
        float iy = (gny + 1.0f) * 0.5f * 511.0f;
        ix = fminf(fmaxf(ix, 0.0f), 511.0f);
        iy = fminf(fmaxf(iy, 0.0f), 511.0f);
        float fx = floorf(ix), fy = floorf(iy);
        float wx = ix - fx, wy = iy - fy;
        int x0 = (int)fx, y0 = (int)fy;
        if (x0 > WW - 2) { x0 = WW - 2; wx = 1.0f; }   // border clamp trick
        if (y0 > HH - 2) { y0 = HH - 2; wy = 1.0f; }
        wxa[k] = wx; wya[k] = wy;
        pre[k] = y0 * 256 + (x0 - wxs);                // pack (y0, xf0)
        x0mn = min(x0mn, x0); x0mx = max(x0mx, x0);
        y0mn = min(y0mn, y0); y0mx = max(y0mx, y0);
    }

    for (int off = 32; off; off >>= 1) {
        x0mn = min(x0mn, __shfl_xor(x0mn, off, 64));
        x0mx = max(x0mx, __shfl_xor(x0mx, off, 64));
        y0mn = min(y0mn, __shfl_xor(y0mn, off, 64));
        y0mx = max(y0mx, __shfl_xor(y0mx, off, 64));
    }
    if ((t & 63) == 0) {
        int wv = t >> 6;
        rx0[wv] = x0mn; rx1[wv] = x0mx; ry0[wv] = y0mn; ry1[wv] = y0mx;
    }
    __syncthreads();
    if (t == 0) {
        int a = rx0[0], bx = rx1[0], c = ry0[0], d = ry1[0];
        #pragma unroll
        for (int i = 1; i < 4; ++i) {
            a = min(a, rx0[i]); bx = max(bx, rx1[i]);
            c = min(c, ry0[i]); d = max(d, ry1[i]);
        }
        int Y0 = c & ~1;                       // even start row
        int Y1r = d + 1;                       // last row needed (<= 511)
        int Ht = Y1r - Y0 + 1;
        int ok = (a >= wxs) && (bx + 1 <= wxs + 127) && (Ht <= 128);
        sbox[0] = ok; sbox[1] = Y0; sbox[2] = Ht;
    }
    __syncthreads();
    int ok = sbox[0], Y0 = sbox[1], Ht = sbox[2];

    const float* xb = xin + (size_t)b * CC * PLANE;
    float* wb = warped + (size_t)b * CC * PLANE;
    int obase = (ty0 + row0) * WW + tx0 + col;

    if (ok) {
        int wave = t >> 6, lane = t & 63;
        int lrow = lane >> 5;
        // swizzle: LDS slot (rw, chunk) holds global chunk (chunk ^ ((rw&7)<<2)).
        // rw = (wave+4i)*2 + lrow  ->  rw&7 = (2*wave + lrow)&7  (lane-constant).
        int s_l = ((wave << 1) + lrow) & 7;
        int lcol4 = ((lane & 31) ^ (s_l << 2)) * 4;    // pre-swizzled source chunk
        const float* gb = xb + (size_t)Y0 * WW + wxs + lrow * WW + lcol4;

        // per-k swizzled sample addresses (channel-invariant)
        int a00[16], a01[16], a10[16], a11[16];
        #pragma unroll
        for (int k = 0; k < 16; ++k) {
            int pk = pre[k];
            int rw0 = (pk >> 8) - Y0;
            int xf0 = pk & 255;
            int rw1 = rw0 + 1;
            int xf1 = xf0 + 1;
            int S0 = (rw0 & 7) << 2, S1 = (rw1 & 7) << 2;
            a00[k] = rw0 * 128 + ((((xf0 >> 2) ^ S0) << 2) | (xf0 & 3));
            a01[k] = rw0 * 128 + ((((xf1 >> 2) ^ S0) << 2) | (xf1 & 3));
            a10[k] = rw1 * 128 + ((((xf0 >> 2) ^ S1) << 2) | (xf0 & 3));
            a11[k] = rw1 * 128 + ((((xf1 >> 2) ^ S1) << 2) | (xf1 & 3));
        }

        for (int c = 0; c < CC; ++c) {
            const float* g = gb + (size_t)c * PLANE;
            #pragma unroll
            for (int i = 0; i < 16; ++i) {                 // pair rows (wave+4i)*2
                int r0 = (wave + 4 * i) * 2;               // wave-uniform
                if (r0 < Ht)
                    gload_lds16(g + r0 * WW, stage + r0 * 128);
            }
            __syncthreads();                               // window c staged
            float* dstc = wb + (size_t)c * PLANE;
            #pragma unroll
            for (int k = 0; k < 16; ++k) {
                float v00 = stage[a00[k]], v01 = stage[a01[k]];
                float v10 = stage[a10[k]], v11 = stage[a11[k]];
                float tp = v00 + wxa[k] * (v01 - v00);
                float bt = v10 + wxa[k] * (v11 - v10);
                dstc[obase + k * 4 * WW] = tp + wya[k] * (bt - tp);
            }
            __syncthreads();                               // reads done before overwrite
        }
    } else {
        // rare fallback: direct global gather (identical arithmetic)
        #pragma unroll
        for (int k = 0; k < 16; ++k) {
            int gy = ty0 + row0 + 4 * k;
            int gx = tx0 + col;
            float dxv = bdx[gy * WW + gx] * sx;
            float dyv = bdy[gy * WW + gx] * sy;
            float gnx = 2.0f * ((float)gx + dxv) / 511.0f - 1.0f;
            float gny = 2.0f * ((float)gy + dyv) / 511.0f - 1.0f;
            float ix = (gnx + 1.0f) * 0.5f * 511.0f;
            float iy = (gny + 1.0f) * 0.5f * 511.0f;
            ix = fminf(fmaxf(ix, 0.0f), 511.0f);
            iy = fminf(fmaxf(iy, 0.0f), 511.0f);
            float fx = floorf(ix), fy = floorf(iy);
            float wx = ix - fx, wy = iy - fy;
            int x0 = (int)fx, y0 = (int)fy;
            if (x0 > WW - 2) { x0 = WW - 2; wx = 1.0f; }
            if (y0 > HH - 2) { y0 = HH - 2; wy = 1.0f; }
            int o00 = y0 * WW + x0;
            for (int c = 0; c < CC; ++c) {
                const float* src = xb + (size_t)c * PLANE;
                float v00 = src[o00], v01 = src[o00 + 1];
                float v10 = src[o00 + WW], v11 = src[o00 + WW + 1];
                float tp = v00 + wx * (v01 - v00);
                float bt = v10 + wx * (v11 - v10);
                wb[(size_t)c * PLANE + obase + k * 4 * WW] = tp + wy * (bt - tp);
            }
        }
    }
}

extern "C" void kernel_launch(void* const* d_in, const int* in_sizes, int n_in,
                              void* d_out, int out_size, void* d_ws, size_t ws_size,
                              hipStream_t stream) {
    const float* x   = (const float*)d_in[0];
    const float* dxn = (const float*)d_in[1];
    const float* dyn = (const float*)d_in[2];

    float* ws = (float*)d_ws;
    float* blur     = ws;                       // 16*512*512 floats
    float* partials = ws + 4194304;             // 512 floats
    float* maxv     = ws + 4194304 + 512;       // 2 floats

    float* warped   = (float*)d_out;
    float2* gridout = (float2*)((float*)d_out + (size_t)BB * CC * PLANE);

    blur_fused_kernel<<<16 * 32, 256, 0, stream>>>(dxn, dyn, blur, partials);
    reduce_max_kernel<<<2, 256, 0, stream>>>(partials, maxv);
    warp_tiled_kernel<<<BB * 64, 256, 0, stream>>>(x, blur, maxv, warped, gridout);
}

// Round 11
// 191.636 us; speedup vs baseline: 1.1997x; 1.0035x over previous
//
#include <hip/hip_runtime.h>
#include <math.h>

#define SIGMA_F 32.0f
#define BB 8
#define CC 31
#define HH 512
#define WW 512
#define PLANE (HH * WW)

// ---- compile-time Gaussian weights: W[i] = exp(-i^2 / 2048) ----
constexpr double cexp_neg(double t) {
    double u = -t / 16.0;
    double s = 1.0, term = 1.0;
    for (int k = 1; k < 14; ++k) { term *= u / (double)k; s += term; }
    s = s * s; s = s * s; s = s * s; s = s * s;
    return s;
}
constexpr float gwf(int i) { return (float)cexp_neg((double)(i * i) / 2048.0); }

__device__ constexpr float W[64] = {
    gwf(0),  gwf(1),  gwf(2),  gwf(3),  gwf(4),  gwf(5),  gwf(6),  gwf(7),
    gwf(8),  gwf(9),  gwf(10), gwf(11), gwf(12), gwf(13), gwf(14), gwf(15),
    gwf(16), gwf(17), gwf(18), gwf(19), gwf(20), gwf(21), gwf(22), gwf(23),
    gwf(24), gwf(25), gwf(26), gwf(27), gwf(28), gwf(29), gwf(30), gwf(31),
    gwf(32), gwf(33), gwf(34), gwf(35), gwf(36), gwf(37), gwf(38), gwf(39),
    gwf(40), gwf(41), gwf(42), gwf(43), gwf(44), gwf(45), gwf(46), gwf(47),
    gwf(48), gwf(49), gwf(50), gwf(51), gwf(52), gwf(53), gwf(54), gwf(55),
    gwf(56), gwf(57), gwf(58), gwf(59), gwf(60), gwf(61), gwf(62), 0.0f
};

__global__ __launch_bounds__(256, 2) void blur_fused_kernel(const float* __restrict__ dxn,
                                                            const float* __restrict__ dyn,
                                                            float* __restrict__ blur,
                                                            float* __restrict__ partials) {
    __shared__ __align__(16) float vt[16 * 580];
    __shared__ float smax[4];
    int t = threadIdx.x;
    int blk = blockIdx.x;
    int plane = blk >> 5;
    int band = blk & 31;
    int y0 = band << 4;
    const float* src = (plane < BB) ? dxn + (size_t)plane * PLANE
                                    : dyn + (size_t)(plane - BB) * PLANE;

    for (int c = t; c < 574; c += 256) {
        int L = c - 31;
        int scol = (L < 0) ? -L : ((L > HH - 1) ? 2 * HH - 2 - L : L);
        float acc[16];
        #pragma unroll
        for (int j = 0; j < 16; ++j) acc[j] = 0.0f;
        #pragma unroll
        for (int ro = 0; ro < 78; ++ro) {
            int rr = y0 - 31 + ro;
            int r = (rr < 0) ? -rr : ((rr > HH - 1) ? 2 * HH - 2 - rr : rr);
            float v = src[r * WW + scol];
            #pragma unroll
            for (int j = 0; j < 16; ++j) {
                int wi = ro - j;
                if (wi >= 0 && wi < 63) acc[j] += W[wi] * v;
            }
        }
        #pragma unroll
        for (int j = 0; j < 16; ++j) vt[j * 580 + c] = acc[j];
    }
    __syncthreads();

    float m = -INFINITY;
    int row = t & 15;
    int chunk0 = t >> 4;
    float* dstrow = blur + (size_t)plane * PLANE + (size_t)(y0 + row) * WW;
    const float* vrow = vt + row * 580;
    #pragma unroll
    for (int pass = 0; pass < 2; ++pass) {
        int x0 = (chunk0 + (pass << 4)) << 4;
        float acc[16];
        #pragma unroll
        for (int j = 0; j < 16; ++j) acc[j] = 0.0f;
        const float4* v4 = (const float4*)(vrow + x0);
        #pragma unroll
        for (int mi = 0; mi < 20; ++mi) {
            float4 vv = v4[mi];
            #pragma unroll
            for (int e = 0; e < 4; ++e) {
                float xv = (e == 0) ? vv.x : (e == 1) ? vv.y : (e == 2) ? vv.z : vv.w;
                int k = (mi << 2) + e;
                #pragma unroll
                for (int j = 0; j < 16; ++j) {
                    int wi = k - j;
                    if (wi >= 0 && wi < 63) acc[j] += W[wi] * xv;
                }
            }
        }
        #pragma unroll
        for (int j = 0; j < 16; ++j) m = fmaxf(m, acc[j]);
        float4* dst4 = (float4*)(dstrow + x0);
        #pragma unroll
        for (int q = 0; q < 4; ++q)
            dst4[q] = make_float4(acc[4 * q], acc[4 * q + 1], acc[4 * q + 2], acc[4 * q + 3]);
    }

    for (int off = 32; off; off >>= 1) m = fmaxf(m, __shfl_down(m, off, 64));
    if ((t & 63) == 0) smax[t >> 6] = m;
    __syncthreads();
    if (t == 0)
        partials[blk] = fmaxf(fmaxf(smax[0], smax[1]), fmaxf(smax[2], smax[3]));
}

__global__ __launch_bounds__(256) void reduce_max_kernel(const float* __restrict__ partials,
                                                         float* __restrict__ maxv) {
    int f = blockIdx.x;
    int t = threadIdx.x;
    float m = partials[f * 256 + t];
    __shared__ float smax[4];
    for (int off = 32; off; off >>= 1) m = fmaxf(m, __shfl_down(m, off, 64));
    if ((t & 63) == 0) smax[t >> 6] = m;
    __syncthreads();
    if (t == 0)
        maxv[f] = fmaxf(fmaxf(smax[0], smax[1]), fmaxf(smax[2], smax[3]));
}

// async global->LDS, 16B per lane; LDS dest = wave-uniform base + lane*16
__device__ __forceinline__ void gload_lds16(const float* g, float* l) {
    __builtin_amdgcn_global_load_lds(
        (const __attribute__((address_space(1))) void*)g,
        (__attribute__((address_space(3))) void*)l,
        16, 0, 0);
}

// Round-8 structure with 512 threads (8 waves) per block: 64x64 tile, 128-col
// window, dynamic row range [Y0, Y0+Ht), 64KB LDS -> 2 blocks/CU = 16 waves/CU
// (was 8). Same total LDS work, 2x the latency hiding for stage drains and
// ds_read chains.
__global__ __launch_bounds__(512) void warp_tiled_kernel(const float* __restrict__ xin,
                                                         const float* __restrict__ blur,
                                                         const float* __restrict__ maxv,
                                                         float* __restrict__ warped,
                                                         float2* __restrict__ gridout) {
    __shared__ __align__(16) float stage[128 * 128];
    __shared__ int rx0[8], rx1[8], ry0[8], ry1[8];
    __shared__ int sbox[3];       // ok, Y0, Ht

    int t = threadIdx.x;
    int bid = blockIdx.x;
    int b = bid & 7;               // XCD j owns batch j
    int tile = bid >> 3;           // row-major tiles within the batch
    int ty0 = (tile >> 3) << 6;
    int tx0 = (tile & 7) << 6;
    int wxs = min(max(tx0 - 32, 0), WW - 128);   // 16B-aligned window start

    float sx = SIGMA_F / maxv[0];
    float sy = SIGMA_F / maxv[1];
    int col = t & 63, row0 = t >> 6;             // row0 in 0..7

    float wxa[8], wya[8];
    int pre[8];
    int x0mn = 1 << 30, x0mx = -1, y0mn = 1 << 30, y0mx = -1;

    const float* bdx = blur + (size_t)b * PLANE;
    const float* bdy = blur + (size_t)(BB + b) * PLANE;

    #pragma unroll
    for (int k = 0; k < 8; ++k) {
        int gy = ty0 + row0 + 8 * k;
        int gx = tx0 + col;
        float dxv = bdx[gy * WW + gx] * sx;
        float dyv = bdy[gy * WW + gx] * sy;
        float gnx = 2.0f * ((float)gx + dxv) / 511.0f - 1.0f;
        float gny = 2.0f * ((float)gy + dyv) / 511.0f - 1.0f;
        gridout[((size_t)b * HH + gy) * WW + gx] = make_float2(gnx, gny);
        float ix = (gnx + 1.0f) * 0.5f * 511.0f;
        float iy = (gny + 1.0f) * 0.5f * 511.0f;
        ix = fminf(fmaxf(ix, 0.0f), 511.0f);
        iy = fminf(fmaxf(iy, 0.0f), 511.0f);
        float fx = floorf(ix), fy = floorf(iy);
        float wx = ix - fx, wy = iy - fy;
        int x0 = (int)fx, y0 = (int)fy;
        if (x0 > WW - 2) { x0 = WW - 2; wx = 1.0f; }   // border clamp trick
        if (y0 > HH - 2) { y0 = HH - 2; wy = 1.0f; }
        wxa[k] = wx; wya[k] = wy;
        pre[k] = y0 * 128 + (x0 - wxs);
        x0mn = min(x0mn, x0); x0mx = max(x0mx, x0);
        y0mn = min(y0mn, y0); y0mx = max(y0mx, y0);
    }

    for (int off = 32; off; off >>= 1) {
        x0mn = min(x0mn, __shfl_xor(x0mn, off, 64));
        x0mx = max(x0mx, __shfl_xor(x0mx, off, 64));
        y0mn = min(y0mn, __shfl_xor(y0mn, off, 64));
        y0mx = max(y0mx, __shfl_xor(y0mx, off, 64));
    }
    if ((t & 63) == 0) {
        int wv = t >> 6;
        rx0[wv] = x0mn; rx1[wv] = x0mx; ry0[wv] = y0mn; ry1[wv] = y0mx;
    }
    __syncthreads();
    if (t == 0) {
        int a = rx0[0], bx = rx1[0], c = ry0[0], d = ry1[0];
        #pragma unroll
        for (int i = 1; i < 8; ++i) {
            a = min(a, rx0[i]); bx = max(bx, rx1[i]);
            c = min(c, ry0[i]); d = max(d, ry1[i]);
        }
        int Y0 = c & ~1;                       // even start row
        int Y1r = d + 1;                       // last row needed (<= 511)
        int Ht = Y1r - Y0 + 1;
        int ok = (a >= wxs) && (bx + 1 <= wxs + 127) && (Ht <= 128);
        sbox[0] = ok; sbox[1] = Y0; sbox[2] = Ht;
    }
    __syncthreads();
    int ok = sbox[0], Y0 = sbox[1], Ht = sbox[2];

    const float* xb = xin + (size_t)b * CC * PLANE;
    float* wb = warped + (size_t)b * CC * PLANE;
    int obase = (ty0 + row0) * WW + tx0 + col;

    if (ok) {
        int wave = t >> 6, lane = t & 63;
        int lrow = lane >> 5, lcol4 = (lane & 31) * 4;
        // lane's address within a 2-row pair: row lrow, 16B chunk lcol4
        const float* gb = xb + (size_t)Y0 * WW + wxs + lrow * WW + lcol4;
        int yoff = Y0 * 128;
        int oa[8];
        #pragma unroll
        for (int k = 0; k < 8; ++k) oa[k] = pre[k] - yoff;

        for (int c = 0; c < CC; ++c) {
            const float* g = gb + (size_t)c * PLANE;
            #pragma unroll
            for (int i = 0; i < 8; ++i) {                  // pair rows (wave+8i)*2
                int r0 = (wave + 8 * i) * 2;               // wave-uniform, 0..126
                if (r0 < Ht)
                    gload_lds16(g + r0 * WW, stage + r0 * 128);
            }
            __syncthreads();                               // window c staged
            float* dstc = wb + (size_t)c * PLANE;
            #pragma unroll
            for (int k = 0; k < 8; ++k) {
                float v00 = stage[oa[k]],       v01 = stage[oa[k] + 1];
                float v10 = stage[oa[k] + 128], v11 = stage[oa[k] + 129];
                float tp = v00 + wxa[k] * (v01 - v00);
                float bt = v10 + wxa[k] * (v11 - v10);
                dstc[obase + k * 8 * WW] = tp + wya[k] * (bt - tp);
            }
            __syncthreads();                               // reads done before overwrite
        }
    } else {
        // rare fallback: direct global gather (identical arithmetic)
        #pragma unroll
        for (int k = 0; k < 8; ++k) {
            int gy = ty0 + row0 + 8 * k;
            int gx = tx0 + col;
            float dxv = bdx[gy * WW + gx] * sx;
            float dyv = bdy[gy * WW + gx] * sy;
            float gnx = 2.0f * ((float)gx + dxv) / 511.0f - 1.0f;
            float gny = 2.0f * ((float)gy + dyv) / 511.0f - 1.0f;
            float ix = (gnx + 1.0f) * 0.5f * 511.0f;
            float iy = (gny + 1.0f) * 0.5f * 511.0f;
            ix = fminf(fmaxf(ix, 0.0f), 511.0f);
            iy = fminf(fmaxf(iy, 0.0f), 511.0f);
            float fx = floorf(ix), fy = floorf(iy);
            float wx = ix - fx, wy = iy - fy;
            int x0 = (int)fx, y0 = (int)fy;
            if (x0 > WW - 2) { x0 = WW - 2; wx = 1.0f; }
            if (y0 > HH - 2) { y0 = HH - 2; wy = 1.0f; }
            int o00 = y0 * WW + x0;
            for (int c = 0; c < CC; ++c) {
                const float* src = xb + (size_t)c * PLANE;
                float v00 = src[o00], v01 = src[o00 + 1];
                float v10 = src[o00 + WW], v11 = src[o00 + WW + 1];
                float tp = v00 + wx * (v01 - v00);
                float bt = v10 + wx * (v11 - v10);
                wb[(size_t)c * PLANE + obase + k * 8 * WW] = tp + wy * (bt - tp);
            }
        }
    }
}

extern "C" void kernel_launch(void* const* d_in, const int* in_sizes, int n_in,
                              void* d_out, int out_size, void* d_ws, size_t ws_size,
                              hipStream_t stream) {
    const float* x   = (const float*)d_in[0];
    const float* dxn = (const float*)d_in[1];
    const float* dyn = (const float*)d_in[2];

    float* ws = (float*)d_ws;
    float* blur     = ws;                       // 16*512*512 floats
    float* partials = ws + 4194304;             // 512 floats
    float* maxv     = ws + 4194304 + 512;       // 2 floats

    float* warped   = (float*)d_out;
    float2* gridout = (float2*)((float*)d_out + (size_t)BB * CC * PLANE);

    blur_fused_kernel<<<16 * 32, 256, 0, stream>>>(dxn, dyn, blur, partials);
    reduce_max_kernel<<<2, 256, 0, stream>>>(partials, maxv);
    warp_tiled_kernel<<<BB * 64, 512, 0, stream>>>(x, blur, maxv, warped, gridout);
}

// Round 12
// 179.398 us; speedup vs baseline: 1.2815x; 1.0682x over previous
//
#include <hip/hip_runtime.h>
#include <math.h>

#define SIGMA_F 32.0f
#define BB 8
#define CC 31
#define HH 512
#define WW 512
#define PLANE (HH * WW)
#define WINR 96                   // 96*128*4B = 48KB -> 3 blocks/CU

// ---- compile-time Gaussian weights: W[i] = exp(-i^2 / 2048) ----
constexpr double cexp_neg(double t) {
    double u = -t / 16.0;
    double s = 1.0, term = 1.0;
    for (int k = 1; k < 14; ++k) { term *= u / (double)k; s += term; }
    s = s * s; s = s * s; s = s * s; s = s * s;
    return s;
}
constexpr float gwf(int i) { return (float)cexp_neg((double)(i * i) / 2048.0); }

__device__ constexpr float W[64] = {
    gwf(0),  gwf(1),  gwf(2),  gwf(3),  gwf(4),  gwf(5),  gwf(6),  gwf(7),
    gwf(8),  gwf(9),  gwf(10), gwf(11), gwf(12), gwf(13), gwf(14), gwf(15),
    gwf(16), gwf(17), gwf(18), gwf(19), gwf(20), gwf(21), gwf(22), gwf(23),
    gwf(24), gwf(25), gwf(26), gwf(27), gwf(28), gwf(29), gwf(30), gwf(31),
    gwf(32), gwf(33), gwf(34), gwf(35), gwf(36), gwf(37), gwf(38), gwf(39),
    gwf(40), gwf(41), gwf(42), gwf(43), gwf(44), gwf(45), gwf(46), gwf(47),
    gwf(48), gwf(49), gwf(50), gwf(51), gwf(52), gwf(53), gwf(54), gwf(55),
    gwf(56), gwf(57), gwf(58), gwf(59), gwf(60), gwf(61), gwf(62), 0.0f
};

__global__ __launch_bounds__(256, 2) void blur_fused_kernel(const float* __restrict__ dxn,
                                                            const float* __restrict__ dyn,
                                                            float* __restrict__ blur,
                                                            float* __restrict__ partials) {
    __shared__ __align__(16) float vt[16 * 580];
    __shared__ float smax[4];
    int t = threadIdx.x;
    int blk = blockIdx.x;
    int plane = blk >> 5;
    int band = blk & 31;
    int y0 = band << 4;
    const float* src = (plane < BB) ? dxn + (size_t)plane * PLANE
                                    : dyn + (size_t)(plane - BB) * PLANE;

    for (int c = t; c < 574; c += 256) {
        int L = c - 31;
        int scol = (L < 0) ? -L : ((L > HH - 1) ? 2 * HH - 2 - L : L);
        float acc[16];
        #pragma unroll
        for (int j = 0; j < 16; ++j) acc[j] = 0.0f;
        #pragma unroll
        for (int ro = 0; ro < 78; ++ro) {
            int rr = y0 - 31 + ro;
            int r = (rr < 0) ? -rr : ((rr > HH - 1) ? 2 * HH - 2 - rr : rr);
            float v = src[r * WW + scol];
            #pragma unroll
            for (int j = 0; j < 16; ++j) {
                int wi = ro - j;
                if (wi >= 0 && wi < 63) acc[j] += W[wi] * v;
            }
        }
        #pragma unroll
        for (int j = 0; j < 16; ++j) vt[j * 580 + c] = acc[j];
    }
    __syncthreads();

    float m = -INFINITY;
    int row = t & 15;
    int chunk0 = t >> 4;
    float* dstrow = blur + (size_t)plane * PLANE + (size_t)(y0 + row) * WW;
    const float* vrow = vt + row * 580;
    #pragma unroll
    for (int pass = 0; pass < 2; ++pass) {
        int x0 = (chunk0 + (pass << 4)) << 4;
        float acc[16];
        #pragma unroll
        for (int j = 0; j < 16; ++j) acc[j] = 0.0f;
        const float4* v4 = (const float4*)(vrow + x0);
        #pragma unroll
        for (int mi = 0; mi < 20; ++mi) {
            float4 vv = v4[mi];
            #pragma unroll
            for (int e = 0; e < 4; ++e) {
                float xv = (e == 0) ? vv.x : (e == 1) ? vv.y : (e == 2) ? vv.z : vv.w;
                int k = (mi << 2) + e;
                #pragma unroll
                for (int j = 0; j < 16; ++j) {
                    int wi = k - j;
                    if (wi >= 0 && wi < 63) acc[j] += W[wi] * xv;
                }
            }
        }
        #pragma unroll
        for (int j = 0; j < 16; ++j) m = fmaxf(m, acc[j]);
        float4* dst4 = (float4*)(dstrow + x0);
        #pragma unroll
        for (int q = 0; q < 4; ++q)
            dst4[q] = make_float4(acc[4 * q], acc[4 * q + 1], acc[4 * q + 2], acc[4 * q + 3]);
    }

    for (int off = 32; off; off >>= 1) m = fmaxf(m, __shfl_down(m, off, 64));
    if ((t & 63) == 0) smax[t >> 6] = m;
    __syncthreads();
    if (t == 0)
        partials[blk] = fmaxf(fmaxf(smax[0], smax[1]), fmaxf(smax[2], smax[3]));
}

__global__ __launch_bounds__(256) void reduce_max_kernel(const float* __restrict__ partials,
                                                         float* __restrict__ maxv) {
    int f = blockIdx.x;
    int t = threadIdx.x;
    float m = partials[f * 256 + t];
    __shared__ float smax[4];
    for (int off = 32; off; off >>= 1) m = fmaxf(m, __shfl_down(m, off, 64));
    if ((t & 63) == 0) smax[t >> 6] = m;
    __syncthreads();
    if (t == 0)
        maxv[f] = fmaxf(fmaxf(smax[0], smax[1]), fmaxf(smax[2], smax[3]));
}

// async global->LDS, 16B per lane; LDS dest = wave-uniform base + lane*16
__device__ __forceinline__ void gload_lds16(const float* g, float* l) {
    __builtin_amdgcn_global_load_lds(
        (const __attribute__((address_space(1))) void*)g,
        (__attribute__((address_space(3))) void*)l,
        16, 0, 0);
}

// 32x64 tile per block, 256 threads, 3 blocks/CU (48KB window). Dynamic row
// range [Y0, Y0+Ht), Ht <= 96 (typical ~50 for a 32-row tile -> fallbacks ~0).
// Three independent barrier domains per CU overlap stage-drain with sampling.
__global__ __launch_bounds__(256, 3) void warp_tiled_kernel(const float* __restrict__ xin,
                                                            const float* __restrict__ blur,
                                                            const float* __restrict__ maxv,
                                                            float* __restrict__ warped,
                                                            float2* __restrict__ gridout) {
    __shared__ __align__(16) float stage[WINR * 128];
    __shared__ int rx0[4], rx1[4], ry0[4], ry1[4];
    __shared__ int sbox[3];       // ok, Y0, Ht

    int t = threadIdx.x;
    int bid = blockIdx.x;          // 1024 blocks = 4 per CU over time
    int b = bid & 7;               // XCD j owns batch j
    int tile = bid >> 3;           // 0..127: 16 row-tiles x 8 col-tiles
    int ty0 = (tile >> 3) << 5;    // 32-row tiles
    int tx0 = (tile & 7) << 6;     // 64-col tiles
    int wxs = min(max(tx0 - 32, 0), WW - 128);   // 16B-aligned window start

    float sx = SIGMA_F / maxv[0];
    float sy = SIGMA_F / maxv[1];
    int col = t & 63, row0 = t >> 6;             // row0 in 0..3

    float wxa[8], wya[8];
    int pre[8];
    int x0mn = 1 << 30, x0mx = -1, y0mn = 1 << 30, y0mx = -1;

    const float* bdx = blur + (size_t)b * PLANE;
    const float* bdy = blur + (size_t)(BB + b) * PLANE;

    #pragma unroll
    for (int k = 0; k < 8; ++k) {
        int gy = ty0 + row0 + 4 * k;             // rows ty0..ty0+31
        int gx = tx0 + col;
        float dxv = bdx[gy * WW + gx] * sx;
        float dyv = bdy[gy * WW + gx] * sy;
        float gnx = 2.0f * ((float)gx + dxv) / 511.0f - 1.0f;
        float gny = 2.0f * ((float)gy + dyv) / 511.0f - 1.0f;
        gridout[((size_t)b * HH + gy) * WW + gx] = make_float2(gnx, gny);
        float ix = (gnx + 1.0f) * 0.5f * 511.0f;
        float iy = (gny + 1.0f) * 0.5f * 511.0f;
        ix = fminf(fmaxf(ix, 0.0f), 511.0f);
        iy = fminf(fmaxf(iy, 0.0f), 511.0f);
        float fx = floorf(ix), fy = floorf(iy);
        float wx = ix - fx, wy = iy - fy;
        int x0 = (int)fx, y0 = (int)fy;
        if (x0 > WW - 2) { x0 = WW - 2; wx = 1.0f; }   // border clamp trick
        if (y0 > HH - 2) { y0 = HH - 2; wy = 1.0f; }
        wxa[k] = wx; wya[k] = wy;
        pre[k] = y0 * 128 + (x0 - wxs);
        x0mn = min(x0mn, x0); x0mx = max(x0mx, x0);
        y0mn = min(y0mn, y0); y0mx = max(y0mx, y0);
    }

    for (int off = 32; off; off >>= 1) {
        x0mn = min(x0mn, __shfl_xor(x0mn, off, 64));
        x0mx = max(x0mx, __shfl_xor(x0mx, off, 64));
        y0mn = min(y0mn, __shfl_xor(y0mn, off, 64));
        y0mx = max(y0mx, __shfl_xor(y0mx, off, 64));
    }
    if ((t & 63) == 0) {
        int wv = t >> 6;
        rx0[wv] = x0mn; rx1[wv] = x0mx; ry0[wv] = y0mn; ry1[wv] = y0mx;
    }
    __syncthreads();
    if (t == 0) {
        int a = rx0[0], bx = rx1[0], c = ry0[0], d = ry1[0];
        #pragma unroll
        for (int i = 1; i < 4; ++i) {
            a = min(a, rx0[i]); bx = max(bx, rx1[i]);
            c = min(c, ry0[i]); d = max(d, ry1[i]);
        }
        int Y0 = c & ~1;                       // even start row
        int Y1r = d + 1;                       // last row needed (<= 511)
        int Ht = Y1r - Y0 + 1;
        int ok = (a >= wxs) && (bx + 1 <= wxs + 127) && (Ht <= WINR);
        sbox[0] = ok; sbox[1] = Y0; sbox[2] = Ht;
    }
    __syncthreads();
    int ok = sbox[0], Y0 = sbox[1], Ht = sbox[2];

    const float* xb = xin + (size_t)b * CC * PLANE;
    float* wb = warped + (size_t)b * CC * PLANE;
    int obase = (ty0 + row0) * WW + tx0 + col;

    if (ok) {
        int wave = t >> 6, lane = t & 63;
        int lrow = lane >> 5, lcol4 = (lane & 31) * 4;
        // lane's address within a 2-row pair: row lrow, 16B chunk lcol4
        const float* gb = xb + (size_t)Y0 * WW + wxs + lrow * WW + lcol4;
        int yoff = Y0 * 128;
        int oa[8];
        #pragma unroll
        for (int k = 0; k < 8; ++k) oa[k] = pre[k] - yoff;

        for (int c = 0; c < CC; ++c) {
            const float* g = gb + (size_t)c * PLANE;
            #pragma unroll
            for (int i = 0; i < 12; ++i) {                 // pair rows (wave+4i)*2 <= 94
                int r0 = (wave + 4 * i) * 2;               // wave-uniform
                if (r0 < Ht)
                    gload_lds16(g + r0 * WW, stage + r0 * 128);
            }
            __syncthreads();                               // window c staged
            float* dstc = wb + (size_t)c * PLANE;
            #pragma unroll
            for (int k = 0; k < 8; ++k) {
                float v00 = stage[oa[k]],       v01 = stage[oa[k] + 1];
                float v10 = stage[oa[k] + 128], v11 = stage[oa[k] + 129];
                float tp = v00 + wxa[k] * (v01 - v00);
                float bt = v10 + wxa[k] * (v11 - v10);
                dstc[obase + k * 4 * WW] = tp + wya[k] * (bt - tp);
            }
            __syncthreads();                               // reads done before overwrite
        }
    } else {
        // rare fallback: direct global gather (identical arithmetic)
        #pragma unroll
        for (int k = 0; k < 8; ++k) {
            int gy = ty0 + row0 + 4 * k;
            int gx = tx0 + col;
            float dxv = bdx[gy * WW + gx] * sx;
            float dyv = bdy[gy * WW + gx] * sy;
            float gnx = 2.0f * ((float)gx + dxv) / 511.0f - 1.0f;
            float gny = 2.0f * ((float)gy + dyv) / 511.0f - 1.0f;
            float ix = (gnx + 1.0f) * 0.5f * 511.0f;
            float iy = (gny + 1.0f) * 0.5f * 511.0f;
            ix = fminf(fmaxf(ix, 0.0f), 511.0f);
            iy = fminf(fmaxf(iy, 0.0f), 511.0f);
            float fx = floorf(ix), fy = floorf(iy);
            float wx = ix - fx, wy = iy - fy;
            int x0 = (int)fx, y0 = (int)fy;
            if (x0 > WW - 2) { x0 = WW - 2; wx = 1.0f; }
            if (y0 > HH - 2) { y0 = HH - 2; wy = 1.0f; }
            int o00 = y0 * WW + x0;
            for (int c = 0; c < CC; ++c) {
                const float* src = xb + (size_t)c * PLANE;
                float v00 = src[o00], v01 = src[o00 + 1];
                float v10 = src[o00 + WW], v11 = src[o00 + WW + 1];
                float tp = v00 + wx * (v01 - v00);
                float bt = v10 + wx * (v11 - v10);
                wb[(size_t)c * PLANE + obase + k * 4 * WW] = tp + wy * (bt - tp);
            }
        }
    }
}

extern "C" void kernel_launch(void* const* d_in, const int* in_sizes, int n_in,
                              void* d_out, int out_size, void* d_ws, size_t ws_size,
                              hipStream_t stream) {
    const float* x   = (const float*)d_in[0];
    const float* dxn = (const float*)d_in[1];
    const float* dyn = (const float*)d_in[2];

    float* ws = (float*)d_ws;
    float* blur     = ws;                       // 16*512*512 floats
    float* partials = ws + 4194304;             // 512 floats
    float* maxv     = ws + 4194304 + 512;       // 2 floats

    float* warped   = (float*)d_out;
    float2* gridout = (float2*)((float*)d_out + (size_t)BB * CC * PLANE);

    blur_fused_kernel<<<16 * 32, 256, 0, stream>>>(dxn, dyn, blur, partials);
    reduce_max_kernel<<<2, 256, 0, stream>>>(partials, maxv);
    warp_tiled_kernel<<<BB * 128, 256, 0, stream>>>(x, blur, maxv, warped, gridout);
}

// Round 14
// 171.072 us; speedup vs baseline: 1.3439x; 1.0487x over previous
//
#include <hip/hip_runtime.h>
#include <math.h>

#define SIGMA_F 32.0f
#define BB 8
#define CC 31
#define HH 512
#define WW 512
#define PLANE (HH * WW)

// ---- compile-time Gaussian weights: W[i] = exp(-i^2 / 2048) ----
constexpr double cexp_neg(double t) {
    double u = -t / 16.0;
    double s = 1.0, term = 1.0;
    for (int k = 1; k < 14; ++k) { term *= u / (double)k; s += term; }
    s = s * s; s = s * s; s = s * s; s = s * s;
    return s;
}
constexpr float gwf(int i) { return (float)cexp_neg((double)(i * i) / 2048.0); }

__device__ constexpr float W[64] = {
    gwf(0),  gwf(1),  gwf(2),  gwf(3),  gwf(4),  gwf(5),  gwf(6),  gwf(7),
    gwf(8),  gwf(9),  gwf(10), gwf(11), gwf(12), gwf(13), gwf(14), gwf(15),
    gwf(16), gwf(17), gwf(18), gwf(19), gwf(20), gwf(21), gwf(22), gwf(23),
    gwf(24), gwf(25), gwf(26), gwf(27), gwf(28), gwf(29), gwf(30), gwf(31),
    gwf(32), gwf(33), gwf(34), gwf(35), gwf(36), gwf(37), gwf(38), gwf(39),
    gwf(40), gwf(41), gwf(42), gwf(43), gwf(44), gwf(45), gwf(46), gwf(47),
    gwf(48), gwf(49), gwf(50), gwf(51), gwf(52), gwf(53), gwf(54), gwf(55),
    gwf(56), gwf(57), gwf(58), gwf(59), gwf(60), gwf(61), gwf(62), 0.0f
};

__global__ __launch_bounds__(256, 2) void blur_fused_kernel(const float* __restrict__ dxn,
                                                            const float* __restrict__ dyn,
                                                            float* __restrict__ blur,
                                                            float* __restrict__ partials) {
    __shared__ __align__(16) float vt[16 * 580];
    __shared__ float smax[4];
    int t = threadIdx.x;
    int blk = blockIdx.x;
    int plane = blk >> 5;
    int band = blk & 31;
    int y0 = band << 4;
    const float* src = (plane < BB) ? dxn + (size_t)plane * PLANE
                                    : dyn + (size_t)(plane - BB) * PLANE;

    for (int c = t; c < 574; c += 256) {
        int L = c - 31;
        int scol = (L < 0) ? -L : ((L > HH - 1) ? 2 * HH - 2 - L : L);
        float acc[16];
        #pragma unroll
        for (int j = 0; j < 16; ++j) acc[j] = 0.0f;
        #pragma unroll
        for (int ro = 0; ro < 78; ++ro) {
            int rr = y0 - 31 + ro;
            int r = (rr < 0) ? -rr : ((rr > HH - 1) ? 2 * HH - 2 - rr : rr);
            float v = src[r * WW + scol];
            #pragma unroll
            for (int j = 0; j < 16; ++j) {
                int wi = ro - j;
                if (wi >= 0 && wi < 63) acc[j] += W[wi] * v;
            }
        }
        #pragma unroll
        for (int j = 0; j < 16; ++j) vt[j * 580 + c] = acc[j];
    }
    __syncthreads();

    float m = -INFINITY;
    int row = t & 15;
    int chunk0 = t >> 4;
    float* dstrow = blur + (size_t)plane * PLANE + (size_t)(y0 + row) * WW;
    const float* vrow = vt + row * 580;
    #pragma unroll
    for (int pass = 0; pass < 2; ++pass) {
        int x0 = (chunk0 + (pass << 4)) << 4;
        float acc[16];
        #pragma unroll
        for (int j = 0; j < 16; ++j) acc[j] = 0.0f;
        const float4* v4 = (const float4*)(vrow + x0);
        #pragma unroll
        for (int mi = 0; mi < 20; ++mi) {
            float4 vv = v4[mi];
            #pragma unroll
            for (int e = 0; e < 4; ++e) {
                float xv = (e == 0) ? vv.x : (e == 1) ? vv.y : (e == 2) ? vv.z : vv.w;
                int k = (mi << 2) + e;
                #pragma unroll
                for (int j = 0; j < 16; ++j) {
                    int wi = k - j;
                    if (wi >= 0 && wi < 63) acc[j] += W[wi] * xv;
                }
            }
        }
        #pragma unroll
        for (int j = 0; j < 16; ++j) m = fmaxf(m, acc[j]);
        float4* dst4 = (float4*)(dstrow + x0);
        #pragma unroll
        for (int q = 0; q < 4; ++q)
            dst4[q] = make_float4(acc[4 * q], acc[4 * q + 1], acc[4 * q + 2], acc[4 * q + 3]);
    }

    for (int off = 32; off; off >>= 1) m = fmaxf(m, __shfl_down(m, off, 64));
    if ((t & 63) == 0) smax[t >> 6] = m;
    __syncthreads();
    if (t == 0)
        partials[blk] = fmaxf(fmaxf(smax[0], smax[1]), fmaxf(smax[2], smax[3]));
}

__global__ __launch_bounds__(256) void reduce_max_kernel(const float* __restrict__ partials,
                                                         float* __restrict__ maxv) {
    int f = blockIdx.x;
    int t = threadIdx.x;
    float m = partials[f * 256 + t];
    __shared__ float smax[4];
    for (int off = 32; off; off >>= 1) m = fmaxf(m, __shfl_down(m, off, 64));
    if ((t & 63) == 0) smax[t >> 6] = m;
    __syncthreads();
    if (t == 0)
        maxv[f] = fmaxf(fmaxf(smax[0], smax[1]), fmaxf(smax[2], smax[3]));
}

// async global->LDS, 16B per lane; LDS dest = wave-uniform base + lane*16
__device__ __forceinline__ void gload_lds16(const float* g, float* l) {
    __builtin_amdgcn_global_load_lds(
        (const __attribute__((address_space(1))) void*)g,
        (__attribute__((address_space(3))) void*)l,
        16, 0, 0);
}
// 4B variant: used as a register-free L2 prefetch into a dummy LDS sink
__device__ __forceinline__ void gload_lds4(const float* g, float* l) {
    __builtin_amdgcn_global_load_lds(
        (const __attribute__((address_space(1))) void*)g,
        (__attribute__((address_space(3))) void*)l,
        4, 0, 0);
}

// Round-8 structure (64x64 tile, 256 thr, 128-row dynamic window, 2 blocks/CU)
// + L2 prefetch of channel c+1 during sample(c), implemented as 3 dummy-sink
// global_load_lds (no VGPR destination -> no register hazard). Counted
// vmcnt(3) leaves exactly the 3 prefetches in flight across the barrier, so
// the next phase's staging drains at L2-hit latency.
__global__ __launch_bounds__(256) void warp_tiled_kernel(const float* __restrict__ xin,
                                                         const float* __restrict__ blur,
                                                         const float* __restrict__ maxv,
                                                         float* __restrict__ warped,
                                                         float2* __restrict__ gridout) {
    __shared__ __align__(16) float stage[128 * 128];
    __shared__ __align__(16) float pfsink[64];   // never read
    __shared__ int rx0[4], rx1[4], ry0[4], ry1[4];
    __shared__ int sbox[3];       // ok, Y0, Ht

    int t = threadIdx.x;
    int bid = blockIdx.x;
    int b = bid & 7;               // XCD j owns batch j
    int tile = bid >> 3;           // row-major tiles within the batch
    int ty0 = (tile >> 3) << 6;
    int tx0 = (tile & 7) << 6;
    int wxs = min(max(tx0 - 32, 0), WW - 128);   // 128B-aligned window start

    float sx = SIGMA_F / maxv[0];
    float sy = SIGMA_F / maxv[1];
    int col = t & 63, row0 = t >> 6;

    float wxa[16], wya[16];
    int pre[16];
    int x0mn = 1 << 30, x0mx = -1, y0mn = 1 << 30, y0mx = -1;

    const float* bdx = blur + (size_t)b * PLANE;
    const float* bdy = blur + (size_t)(BB + b) * PLANE;

    #pragma unroll
    for (int k = 0; k < 16; ++k) {
        int gy = ty0 + row0 + 4 * k;
        int gx = tx0 + col;
        float dxv = bdx[gy * WW + gx] * sx;
        float dyv = bdy[gy * WW + gx] * sy;
        float gnx = 2.0f * ((float)gx + dxv) / 511.0f - 1.0f;
        float gny = 2.0f * ((float)gy + dyv) / 511.0f - 1.0f;
        gridout[((size_t)b * HH + gy) * WW + gx] = make_float2(gnx, gny);
        float ix = (gnx + 1.0f) * 0.5f * 511.0f;
        float iy = (gny + 1.0f) * 0.5f * 511.0f;
        ix = fminf(fmaxf(ix, 0.0f), 511.0f);
        iy = fminf(fmaxf(iy, 0.0f), 511.0f);
        float fx = floorf(ix), fy = floorf(iy);
        float wx = ix - fx, wy = iy - fy;
        int x0 = (int)fx, y0 = (int)fy;
        if (x0 > WW - 2) { x0 = WW - 2; wx = 1.0f; }   // border clamp trick
        if (y0 > HH - 2) { y0 = HH - 2; wy = 1.0f; }
        wxa[k] = wx; wya[k] = wy;
        pre[k] = y0 * 128 + (x0 - wxs);
        x0mn = min(x0mn, x0); x0mx = max(x0mx, x0);
        y0mn = min(y0mn, y0); y0mx = max(y0mx, y0);
    }

    for (int off = 32; off; off >>= 1) {
        x0mn = min(x0mn, __shfl_xor(x0mn, off, 64));
        x0mx = max(x0mx, __shfl_xor(x0mx, off, 64));
        y0mn = min(y0mn, __shfl_xor(y0mn, off, 64));
        y0mx = max(y0mx, __shfl_xor(y0mx, off, 64));
    }
    if ((t & 63) == 0) {
        int wv = t >> 6;
        rx0[wv] = x0mn; rx1[wv] = x0mx; ry0[wv] = y0mn; ry1[wv] = y0mx;
    }
    __syncthreads();
    if (t == 0) {
        int a = rx0[0], bx = rx1[0], c = ry0[0], d = ry1[0];
        #pragma unroll
        for (int i = 1; i < 4; ++i) {
            a = min(a, rx0[i]); bx = max(bx, rx1[i]);
            c = min(c, ry0[i]); d = max(d, ry1[i]);
        }
        int Y0 = c & ~1;                       // even start row
        int Y1r = d + 1;                       // last row needed (<= 511)
        int Ht = Y1r - Y0 + 1;
        int ok = (a >= wxs) && (bx + 1 <= wxs + 127) && (Ht <= 128);
        sbox[0] = ok; sbox[1] = Y0; sbox[2] = Ht;
    }
    __syncthreads();
    int ok = sbox[0], Y0 = sbox[1], Ht = sbox[2];

    const float* xb = xin + (size_t)b * CC * PLANE;
    float* wb = warped + (size_t)b * CC * PLANE;
    int obase = (ty0 + row0) * WW + tx0 + col;

    if (ok) {
        int wave = t >> 6, lane = t & 63;
        int lrow = lane >> 5, lcol4 = (lane & 31) * 4;
        // lane's address within a 2-row pair: row lrow, 16B chunk lcol4
        const float* gb = xb + (size_t)Y0 * WW + wxs + lrow * WW + lcol4;
        const float* pfbase = xb + (size_t)Y0 * WW + wxs;   // window origin
        int yoff = Y0 * 128;
        int oa[16];
        #pragma unroll
        for (int k = 0; k < 16; ++k) oa[k] = pre[k] - yoff;

        int nl = (Ht << 3) - 1;              // last 64B-line index of a window

        for (int c = 0; c < CC; ++c) {
            const float* g = gb + (size_t)c * PLANE;
            #pragma unroll
            for (int i = 0; i < 16; ++i) {                 // pair rows (wave+4i)*2
                int r0 = (wave + 4 * i) * 2;               // wave-uniform
                if (r0 < Ht)
                    gload_lds16(g + r0 * WW, stage + r0 * 128);
            }
            if (c + 1 < CC) {
                // register-free L2 prefetch: one dword per 64B line, dummy sink
                const float* pf = pfbase + (size_t)(c + 1) * PLANE;
                int i0 = min(t, nl), i1 = min(t + 256, nl), i2 = min(t + 512, nl);
                gload_lds4(pf + (i0 >> 3) * WW + ((i0 & 7) << 4), pfsink);
                gload_lds4(pf + (i1 >> 3) * WW + ((i1 & 7) << 4), pfsink);
                gload_lds4(pf + (i2 >> 3) * WW + ((i2 & 7) << 4), pfsink);
                __builtin_amdgcn_sched_barrier(0);
                asm volatile("s_waitcnt vmcnt(3)" ::: "memory");  // stage(c) drained
            } else {
                asm volatile("s_waitcnt vmcnt(0)" ::: "memory");
            }
            __builtin_amdgcn_sched_barrier(0);
            __builtin_amdgcn_s_barrier();                  // window c staged
            __builtin_amdgcn_sched_barrier(0);

            float* dstc = wb + (size_t)c * PLANE;
            #pragma unroll
            for (int k = 0; k < 16; ++k) {
                float v00 = stage[oa[k]],       v01 = stage[oa[k] + 1];
                float v10 = stage[oa[k] + 128], v11 = stage[oa[k] + 129];
                float tp = v00 + wxa[k] * (v01 - v00);
                float bt = v10 + wxa[k] * (v11 - v10);
                dstc[obase + k * 4 * WW] = tp + wya[k] * (bt - tp);
            }
            __builtin_amdgcn_sched_barrier(0);
            asm volatile("s_waitcnt lgkmcnt(0)" ::: "memory");  // my stage reads done
            __builtin_amdgcn_s_barrier();                  // buffer reusable
            __builtin_amdgcn_sched_barrier(0);
        }
    } else {
        // rare fallback: direct global gather (identical arithmetic)
        #pragma unroll
        for (int k = 0; k < 16; ++k) {
            int gy = ty0 + row0 + 4 * k;
            int gx = tx0 + col;
            float dxv = bdx[gy * WW + gx] * sx;
            float dyv = bdy[gy * WW + gx] * sy;
            float gnx = 2.0f * ((float)gx + dxv) / 511.0f - 1.0f;
            float gny = 2.0f * ((float)gy + dyv) / 511.0f - 1.0f;
            float ix = (gnx + 1.0f) * 0.5f * 511.0f;
            float iy = (gny + 1.0f) * 0.5f * 511.0f;
            ix = fminf(fmaxf(ix, 0.0f), 511.0f);
            iy = fminf(fmaxf(iy, 0.0f), 511.0f);
            float fx = floorf(ix), fy = floorf(iy);
            float wx = ix - fx, wy = iy - fy;
            int x0 = (int)fx, y0 = (int)fy;
            if (x0 > WW - 2) { x0 = WW - 2; wx = 1.0f; }
            if (y0 > HH - 2) { y0 = HH - 2; wy = 1.0f; }
            int o00 = y0 * WW + x0;
            for (int c = 0; c < CC; ++c) {
                const float* src = xb + (size_t)c * PLANE;
                float v00 = src[o00], v01 = src[o00 + 1];
                float v10 = src[o00 + WW], v11 = src[o00 + WW + 1];
                float tp = v00 + wx * (v01 - v00);
                float bt = v10 + wx * (v11 - v10);
                wb[(size_t)c * PLANE + obase + k * 4 * WW] = tp + wy * (bt - tp);
            }
        }
    }
}

extern "C" void kernel_launch(void* const* d_in, const int* in_sizes, int n_in,
                              void* d_out, int out_size, void* d_ws, size_t ws_size,
                              hipStream_t stream) {
    const float* x   = (const float*)d_in[0];
    const float* dxn = (const float*)d_in[1];
    const float* dyn = (const float*)d_in[2];

    float* ws = (float*)d_ws;
    float* blur     = ws;                       // 16*512*512 floats
    float* partials = ws + 4194304;             // 512 floats
    float* maxv     = ws + 4194304 + 512;       // 2 floats

    float* warped   = (float*)d_out;
    float2* gridout = (float2*)((float*)d_out + (size_t)BB * CC * PLANE);

    blur_fused_kernel<<<16 * 32, 256, 0, stream>>>(dxn, dyn, blur, partials);
    reduce_max_kernel<<<2, 256, 0, stream>>>(partials, maxv);
    warp_tiled_kernel<<<BB * 64, 256, 0, stream>>>(x, blur, maxv, warped, gridout);
}

// Round 15
// 146.826 us; speedup vs baseline: 1.5658x; 1.1651x over previous
//
#include <hip/hip_runtime.h>
#include <math.h>

#define SIGMA_F 32.0f
#define BB 8
#define CC 31
#define HH 512
#define WW 512
#define PLANE (HH * WW)

// ---- compile-time Gaussian weights: W[i] = exp(-i^2 / 2048) ----
constexpr double cexp_neg(double t) {
    double u = -t / 16.0;
    double s = 1.0, term = 1.0;
    for (int k = 1; k < 14; ++k) { term *= u / (double)k; s += term; }
    s = s * s; s = s * s; s = s * s; s = s * s;
    return s;
}
constexpr float gwf(int i) { return (float)cexp_neg((double)(i * i) / 2048.0); }

__device__ constexpr float W[64] = {
    gwf(0),  gwf(1),  gwf(2),  gwf(3),  gwf(4),  gwf(5),  gwf(6),  gwf(7),
    gwf(8),  gwf(9),  gwf(10), gwf(11), gwf(12), gwf(13), gwf(14), gwf(15),
    gwf(16), gwf(17), gwf(18), gwf(19), gwf(20), gwf(21), gwf(22), gwf(23),
    gwf(24), gwf(25), gwf(26), gwf(27), gwf(28), gwf(29), gwf(30), gwf(31),
    gwf(32), gwf(33), gwf(34), gwf(35), gwf(36), gwf(37), gwf(38), gwf(39),
    gwf(40), gwf(41), gwf(42), gwf(43), gwf(44), gwf(45), gwf(46), gwf(47),
    gwf(48), gwf(49), gwf(50), gwf(51), gwf(52), gwf(53), gwf(54), gwf(55),
    gwf(56), gwf(57), gwf(58), gwf(59), gwf(60), gwf(61), gwf(62), 0.0f
};

__global__ __launch_bounds__(256, 2) void blur_fused_kernel(const float* __restrict__ dxn,
                                                            const float* __restrict__ dyn,
                                                            float* __restrict__ blur,
                                                            float* __restrict__ partials) {
    __shared__ __align__(16) float vt[16 * 580];
    __shared__ float smax[4];
    int t = threadIdx.x;
    int blk = blockIdx.x;
    int plane = blk >> 5;
    int band = blk & 31;
    int y0 = band << 4;
    const float* src = (plane < BB) ? dxn + (size_t)plane * PLANE
                                    : dyn + (size_t)(plane - BB) * PLANE;

    for (int c = t; c < 574; c += 256) {
        int L = c - 31;
        int scol = (L < 0) ? -L : ((L > HH - 1) ? 2 * HH - 2 - L : L);
        float acc[16];
        #pragma unroll
        for (int j = 0; j < 16; ++j) acc[j] = 0.0f;
        #pragma unroll
        for (int ro = 0; ro < 78; ++ro) {
            int rr = y0 - 31 + ro;
            int r = (rr < 0) ? -rr : ((rr > HH - 1) ? 2 * HH - 2 - rr : rr);
            float v = src[r * WW + scol];
            #pragma unroll
            for (int j = 0; j < 16; ++j) {
                int wi = ro - j;
                if (wi >= 0 && wi < 63) acc[j] += W[wi] * v;
            }
        }
        #pragma unroll
        for (int j = 0; j < 16; ++j) vt[j * 580 + c] = acc[j];
    }
    __syncthreads();

    float m = -INFINITY;
    int row = t & 15;
    int chunk0 = t >> 4;
    float* dstrow = blur + (size_t)plane * PLANE + (size_t)(y0 + row) * WW;
    const float* vrow = vt + row * 580;
    #pragma unroll
    for (int pass = 0; pass < 2; ++pass) {
        int x0 = (chunk0 + (pass << 4)) << 4;
        float acc[16];
        #pragma unroll
        for (int j = 0; j < 16; ++j) acc[j] = 0.0f;
        const float4* v4 = (const float4*)(vrow + x0);
        #pragma unroll
        for (int mi = 0; mi < 20; ++mi) {
            float4 vv = v4[mi];
            #pragma unroll
            for (int e = 0; e < 4; ++e) {
                float xv = (e == 0) ? vv.x : (e == 1) ? vv.y : (e == 2) ? vv.z : vv.w;
                int k = (mi << 2) + e;
                #pragma unroll
                for (int j = 0; j < 16; ++j) {
                    int wi = k - j;
                    if (wi >= 0 && wi < 63) acc[j] += W[wi] * xv;
                }
            }
        }
        #pragma unroll
        for (int j = 0; j < 16; ++j) m = fmaxf(m, acc[j]);
        float4* dst4 = (float4*)(dstrow + x0);
        #pragma unroll
        for (int q = 0; q < 4; ++q)
            dst4[q] = make_float4(acc[4 * q], acc[4 * q + 1], acc[4 * q + 2], acc[4 * q + 3]);
    }

    for (int off = 32; off; off >>= 1) m = fmaxf(m, __shfl_down(m, off, 64));
    if ((t & 63) == 0) smax[t >> 6] = m;
    __syncthreads();
    if (t == 0)
        partials[blk] = fmaxf(fmaxf(smax[0], smax[1]), fmaxf(smax[2], smax[3]));
}

__global__ __launch_bounds__(256) void reduce_max_kernel(const float* __restrict__ partials,
                                                         float* __restrict__ maxv) {
    int f = blockIdx.x;
    int t = threadIdx.x;
    float m = partials[f * 256 + t];
    __shared__ float smax[4];
    for (int off = 32; off; off >>= 1) m = fmaxf(m, __shfl_down(m, off, 64));
    if ((t & 63) == 0) smax[t >> 6] = m;
    __syncthreads();
    if (t == 0)
        maxv[f] = fmaxf(fmaxf(smax[0], smax[1]), fmaxf(smax[2], smax[3]));
}

// async global->LDS, 16B per lane; LDS dest = wave-uniform base + lane*16
__device__ __forceinline__ void gload_lds16(const float* g, float* l) {
    __builtin_amdgcn_global_load_lds(
        (const __attribute__((address_space(1))) void*)g,
        (__attribute__((address_space(3))) void*)l,
        16, 0, 0);
}

// 64x64 tile per block, 256 threads, 2 blocks/CU (round-8 best configuration).
// DYNAMIC row window: per-tile reduce gives Y0 (even) and Ht; only the Ht
// rows actually addressed are staged (pairs of rows per gload_lds16, with a
// wave-uniform predicate). X window fixed 128 cols, aligned. Fallback to
// direct gather only if the x-span escapes the 128-col window or Ht > 128.
__global__ __launch_bounds__(256) void warp_tiled_kernel(const float* __restrict__ xin,
                                                         const float* __restrict__ blur,
                                                         const float* __restrict__ maxv,
                                                         float* __restrict__ warped,
                                                         float2* __restrict__ gridout) {
    __shared__ __align__(16) float stage[128 * 128];
    __shared__ int rx0[4], rx1[4], ry0[4], ry1[4];
    __shared__ int sbox[3];       // ok, Y0, Ht

    int t = threadIdx.x;
    int bid = blockIdx.x;
    int b = bid & 7;               // XCD j owns batch j
    int tile = bid >> 3;           // row-major tiles within the batch
    int ty0 = (tile >> 3) << 6;
    int tx0 = (tile & 7) << 6;
    int wxs = min(max(tx0 - 32, 0), WW - 128);   // 16B-aligned window start

    float sx = SIGMA_F / maxv[0];
    float sy = SIGMA_F / maxv[1];
    int col = t & 63, row0 = t >> 6;

    float wxa[16], wya[16];
    int pre[16];
    int x0mn = 1 << 30, x0mx = -1, y0mn = 1 << 30, y0mx = -1;

    const float* bdx = blur + (size_t)b * PLANE;
    const float* bdy = blur + (size_t)(BB + b) * PLANE;

    #pragma unroll
    for (int k = 0; k < 16; ++k) {
        int gy = ty0 + row0 + 4 * k;
        int gx = tx0 + col;
        float dxv = bdx[gy * WW + gx] * sx;
        float dyv = bdy[gy * WW + gx] * sy;
        float gnx = 2.0f * ((float)gx + dxv) / 511.0f - 1.0f;
        float gny = 2.0f * ((float)gy + dyv) / 511.0f - 1.0f;
        gridout[((size_t)b * HH + gy) * WW + gx] = make_float2(gnx, gny);
        float ix = (gnx + 1.0f) * 0.5f * 511.0f;
        float iy = (gny + 1.0f) * 0.5f * 511.0f;
        ix = fminf(fmaxf(ix, 0.0f), 511.0f);
        iy = fminf(fmaxf(iy, 0.0f), 511.0f);
        float fx = floorf(ix), fy = floorf(iy);
        float wx = ix - fx, wy = iy - fy;
        int x0 = (int)fx, y0 = (int)fy;
        if (x0 > WW - 2) { x0 = WW - 2; wx = 1.0f; }   // border clamp trick
        if (y0 > HH - 2) { y0 = HH - 2; wy = 1.0f; }
        wxa[k] = wx; wya[k] = wy;
        pre[k] = y0 * 128 + (x0 - wxs);
        x0mn = min(x0mn, x0); x0mx = max(x0mx, x0);
        y0mn = min(y0mn, y0); y0mx = max(y0mx, y0);
    }

    for (int off = 32; off; off >>= 1) {
        x0mn = min(x0mn, __shfl_xor(x0mn, off, 64));
        x0mx = max(x0mx, __shfl_xor(x0mx, off, 64));
        y0mn = min(y0mn, __shfl_xor(y0mn, off, 64));
        y0mx = max(y0mx, __shfl_xor(y0mx, off, 64));
    }
    if ((t & 63) == 0) {
        int wv = t >> 6;
        rx0[wv] = x0mn; rx1[wv] = x0mx; ry0[wv] = y0mn; ry1[wv] = y0mx;
    }
    __syncthreads();
    if (t == 0) {
        int a = rx0[0], bx = rx1[0], c = ry0[0], d = ry1[0];
        #pragma unroll
        for (int i = 1; i < 4; ++i) {
            a = min(a, rx0[i]); bx = max(bx, rx1[i]);
            c = min(c, ry0[i]); d = max(d, ry1[i]);
        }
        int Y0 = c & ~1;                       // even start row
        int Y1r = d + 1;                       // last row needed (<= 511)
        int Ht = Y1r - Y0 + 1;
        int ok = (a >= wxs) && (bx + 1 <= wxs + 127) && (Ht <= 128);
        sbox[0] = ok; sbox[1] = Y0; sbox[2] = Ht;
    }
    __syncthreads();
    int ok = sbox[0], Y0 = sbox[1], Ht = sbox[2];

    const float* xb = xin + (size_t)b * CC * PLANE;
    float* wb = warped + (size_t)b * CC * PLANE;
    int obase = (ty0 + row0) * WW + tx0 + col;

    if (ok) {
        int wave = t >> 6, lane = t & 63;
        int lrow = lane >> 5, lcol4 = (lane & 31) * 4;
        // lane's address within a 2-row pair: row lrow, 16B chunk lcol4
        const float* gb = xb + (size_t)Y0 * WW + wxs + lrow * WW + lcol4;
        int yoff = Y0 * 128;
        int oa[16];
        #pragma unroll
        for (int k = 0; k < 16; ++k) oa[k] = pre[k] - yoff;

        for (int c = 0; c < CC; ++c) {
            const float* g = gb + (size_t)c * PLANE;
            #pragma unroll
            for (int i = 0; i < 16; ++i) {
                int r0 = (wave + 4 * i) * 2;               // wave-uniform pair row
                if (r0 < Ht)
                    gload_lds16(g + r0 * WW, stage + r0 * 128);
            }
            __syncthreads();                               // window c staged
            float* dstc = wb + (size_t)c * PLANE;
            #pragma unroll
            for (int k = 0; k < 16; ++k) {
                float v00 = stage[oa[k]],       v01 = stage[oa[k] + 1];
                float v10 = stage[oa[k] + 128], v11 = stage[oa[k] + 129];
                float tp = v00 + wxa[k] * (v01 - v00);
                float bt = v10 + wxa[k] * (v11 - v10);
                dstc[obase + k * 4 * WW] = tp + wya[k] * (bt - tp);
            }
            __syncthreads();                               // reads done before overwrite
        }
    } else {
        // rare fallback: direct global gather (identical arithmetic)
        #pragma unroll
        for (int k = 0; k < 16; ++k) {
            int gy = ty0 + row0 + 4 * k;
            int gx = tx0 + col;
            float dxv = bdx[gy * WW + gx] * sx;
            float dyv = bdy[gy * WW + gx] * sy;
            float gnx = 2.0f * ((float)gx + dxv) / 511.0f - 1.0f;
            float gny = 2.0f * ((float)gy + dyv) / 511.0f - 1.0f;
            float ix = (gnx + 1.0f) * 0.5f * 511.0f;
            float iy = (gny + 1.0f) * 0.5f * 511.0f;
            ix = fminf(fmaxf(ix, 0.0f), 511.0f);
            iy = fminf(fmaxf(iy, 0.0f), 511.0f);
            float fx = floorf(ix), fy = floorf(iy);
            float wx = ix - fx, wy = iy - fy;
            int x0 = (int)fx, y0 = (int)fy;
            if (x0 > WW - 2) { x0 = WW - 2; wx = 1.0f; }
            if (y0 > HH - 2) { y0 = HH - 2; wy = 1.0f; }
            int o00 = y0 * WW + x0;
            for (int c = 0; c < CC; ++c) {
                const float* src = xb + (size_t)c * PLANE;
                float v00 = src[o00], v01 = src[o00 + 1];
                float v10 = src[o00 + WW], v11 = src[o00 + WW + 1];
                float tp = v00 + wx * (v01 - v00);
                float bt = v10 + wx * (v11 - v10);
                wb[(size_t)c * PLANE + obase + k * 4 * WW] = tp + wy * (bt - tp);
            }
        }
    }
}

extern "C" void kernel_launch(void* const* d_in, const int* in_sizes, int n_in,
                              void* d_out, int out_size, void* d_ws, size_t ws_size,
                              hipStream_t stream) {
    const float* x   = (const float*)d_in[0];
    const float* dxn = (const float*)d_in[1];
    const float* dyn = (const float*)d_in[2];

    float* ws = (float*)d_ws;
    float* blur     = ws;                       // 16*512*512 floats
    float* partials = ws + 4194304;             // 512 floats
    float* maxv     = ws + 4194304 + 512;       // 2 floats

    float* warped   = (float*)d_out;
    float2* gridout = (float2*)((float*)d_out + (size_t)BB * CC * PLANE);

    blur_fused_kernel<<<16 * 32, 256, 0, stream>>>(dxn, dyn, blur, partials);
    reduce_max_kernel<<<2, 256, 0, stream>>>(partials, maxv);
    warp_tiled_kernel<<<BB * 64, 256, 0, stream>>>(x, blur, maxv, warped, gridout);
}